// Round 7
// baseline (139.678 us; speedup 1.0000x reference)
//
#include <hip/hip_runtime.h>

// PendulumSolver: B=65536 independent driven pendulums, RK4, 999 steps.
// Round 7: software-pipeline the forcing trig (c1,c2,c4) ONE STEP AHEAD.
// They depend only on the step index, so each step issues the next step's
// forcing reductions + v_cos evals (independent work, ~16 VALU + 3 trans)
// before running the current step's serial theta chain — the scheduler fills
// the chain's trans/fma latency bubbles (R6: 27% stall @ 1 wave/SIMD, no TLP).
// Numerics BIT-IDENTICAL to round 6 (same expressions, same order; only
// instruction scheduling changes): all trig args (th, th2, th3, th4, tp*t,
// tp*(t+hdt), tp*(t+dt)) unchanged; CW-split radians->revolutions reduction
// (error ~1.2e-7 rev independent of |x|) + HW v_sin/v_cos. absmax has been
// frozen at 0.0625 across six implementations in this eval-error class.

typedef float v2f __attribute__((ext_vector_type(2)));

__device__ __forceinline__ v2f vfma2(v2f a, v2f b, v2f c) {
#if __has_builtin(__builtin_elementwise_fma)
    return __builtin_elementwise_fma(a, b, c);
#else
    v2f r; r.x = fmaf(a.x, b.x, c.x); r.y = fmaf(a.y, b.y, c.y); return r;
#endif
}
__device__ __forceinline__ v2f splat2(float v) { v2f r; r.x = v; r.y = v; return r; }

#define CHI_F 0.15915494309189533577f
#define CLO_F ((float)(0.15915494309189533577 - (double)0.15915494309189533577f))
#define MAGIC_F 12582912.0f   // 1.5 * 2^23

// radians -> revolutions in [-0.5, 0.5]; error ~1.2e-7 rev independent of |x|.
__device__ __forceinline__ v2f to_rev2(v2f x) {
    v2f nb = vfma2(x, splat2(CHI_F), splat2(MAGIC_F));
    v2f n  = nb - splat2(MAGIC_F);
    v2f r  = vfma2(x, splat2(CHI_F), -n);    // product exact inside fma
    r = vfma2(x, splat2(CLO_F), r);
    return r;
}
__device__ __forceinline__ float to_rev1(float x) {
    float nb = fmaf(x, CHI_F, MAGIC_F);
    float n  = nb - MAGIC_F;
    float r  = fmaf(x, CHI_F, -n);
    return fmaf(x, CLO_F, r);
}

__device__ __forceinline__ float hw_sin_rev(float x) {
#if __has_builtin(__builtin_amdgcn_sinf)
    return __builtin_amdgcn_sinf(x);
#else
    return __sinf(x * 6.28318530717958647692f);
#endif
}
__device__ __forceinline__ float hw_cos_rev(float x) {
#if __has_builtin(__builtin_amdgcn_cosf)
    return __builtin_amdgcn_cosf(x);
#else
    return __cosf(x * 6.28318530717958647692f);
#endif
}

__global__ __launch_bounds__(256) void pend_kernel(
    const float* __restrict__ init,    // (B,2) theta, thdot
    const float* __restrict__ params,  // (B,4) omega, gamma, A, phi
    float* __restrict__ out,           // (B,1000)
    int B)
{
    int b = blockIdx.x * blockDim.x + threadIdx.x;
    if (b >= B) return;

    float th = init[2 * b + 0];
    float w  = init[2 * b + 1];
    const float omega = params[4 * b + 0];
    const float gamma = params[4 * b + 1];
    const float A     = params[4 * b + 2];
    const float phi   = params[4 * b + 3];

    const float dt  = 0.01f;
    const float hdt = 0.5f * dt;
    const float dt6 = dt / 6.0f;
    const float om2 = omega * omega;
    const float Fco = (A * omega) * omega;
    const float tp  = 6.28318530717958647692f * phi;

    float4* out4 = (float4*)(out + (size_t)b * 1000);

    // Forcing cosines for time index fkv (t = fkv*dt), bit-identical to R6.
    auto forcing = [&](float fkv, float& c1o, float& c2o, float& c4o) {
        float t  = fkv * dt;               // == (float)k * dt bit-exact
        float t2 = t + hdt;
        float t3 = t + dt;
        v2f y12; y12.x = tp * t; y12.y = tp * t2;
        float y3 = tp * t3;
        v2f rB   = to_rev2(y12);
        float r3 = to_rev1(y3);
        c1o = hw_cos_rev(rB.x);
        c2o = hw_cos_rev(rB.y);            // shared by stages 2 and 3
        c4o = hw_cos_rev(r3);
    };

    float fk = 0.0f;                       // tracks (float)k exactly
    float c1c, c2c, c4c;
    forcing(fk, c1c, c2c, c4c);            // prologue: step-0 forcing

    auto step = [&]() -> float {
        float c1 = c1c, c2 = c2c, c4 = c4c;
        fk += 1.0f;
        forcing(fk, c1c, c2c, c4c);        // NEXT step's forcing: independent,
                                           // fills current chain's bubbles
        float th2 = fmaf(hdt, w, th);
        v2f ra; ra.x = th; ra.y = th2;
        v2f rA = to_rev2(ra);
        float sth = hw_sin_rev(rA.x);
        float s2  = hw_sin_rev(rA.y);

        float a1  = Fco * c1 - gamma * w   - om2 * sth;
        float w2_ = fmaf(hdt, a1, w);
        float a2  = Fco * c2 - gamma * w2_ - om2 * s2;
        float th3 = fmaf(hdt, w2_, th);
        float s3  = hw_sin_rev(to_rev1(th3));
        float w3_ = fmaf(hdt, a2, w);
        float a3  = Fco * c2 - gamma * w3_ - om2 * s3;
        float th4 = fmaf(dt, w3_, th);
        float s4  = hw_sin_rev(to_rev1(th4));
        float w4_ = fmaf(dt, a3, w);
        float a4  = Fco * c4 - gamma * w4_ - om2 * s4;

        float ks_th = w  + 2.0f * w2_ + 2.0f * w3_ + w4_;
        float ks_w  = a1 + 2.0f * a2  + 2.0f * a3  + a4;
        th = fmaf(dt6, ks_th, th);
        w  = fmaf(dt6, ks_w,  w);
        return th;
    };

    float4 ob;
    ob.x = th;
    ob.y = step();
    ob.z = step();
    ob.w = step();
    out4[0] = ob;

    for (int c = 1; c < 250; ++c) {
        ob.x = step();
        ob.y = step();
        ob.z = step();
        ob.w = step();
        out4[c] = ob;
    }
}

extern "C" void kernel_launch(void* const* d_in, const int* in_sizes, int n_in,
                              void* d_out, int out_size, void* d_ws, size_t ws_size,
                              hipStream_t stream) {
    const float* init   = (const float*)d_in[0];
    const float* params = (const float*)d_in[1];
    float* out = (float*)d_out;
    int B = in_sizes[0] / 2;

    int block = 256;
    int grid  = (B + block - 1) / block;
    hipLaunchKernelGGL(pend_kernel, dim3(grid), dim3(block), 0, stream,
                       init, params, out, B);
}